// Round 7
// baseline (591.180 us; speedup 1.0000x reference)
//
#include <hip/hip_runtime.h>
#include <hip/hip_bf16.h>

#define N_SRC  200000
#define N_MIDN 40000
#define N_DSTN 8000
#define RREL   4
#define E1N    1000000
#define E2N    200000
#define CAP    96    // ELL capacity; mean degree 25, overflow prob negligible
#define EPB    8192  // edges per count/scatter block

typedef __attribute__((ext_vector_type(8))) short bf16x8;
typedef __attribute__((ext_vector_type(4))) float f32x4;
typedef __attribute__((ext_vector_type(4))) unsigned short u16x4;

__device__ __forceinline__ unsigned short f2bf(float f) {
    unsigned int u = __float_as_uint(f);
    u = (u + 0x7FFFu + ((u >> 16) & 1u)) >> 16;   // RNE
    return (unsigned short)u;
}

__device__ __forceinline__ float bflo(unsigned int u) { return __uint_as_float(u << 16); }
__device__ __forceinline__ float bfhi(unsigned int u) { return __uint_as_float(u & 0xFFFF0000u); }

__device__ __forceinline__ void gload_lds16(const void* g, void* l) {
    __builtin_amdgcn_global_load_lds((const __attribute__((address_space(1))) void*)g,
                                     (__attribute__((address_space(3))) void*)l, 16, 0, 0);
}

// ---------------------------------------------------------------------------
// Phase 1: per-(relation, 8K-edge block) LDS byte histogram of dst.
// ---------------------------------------------------------------------------
__global__ __launch_bounds__(256) void count_kernel(
    const int* __restrict__ dst, unsigned char* __restrict__ rank8,
    unsigned int* __restrict__ hist, int epr, int ndst4, int nb)
{
    __shared__ unsigned int cnt4[10240];   // up to 40960 nodes as packed u8
    const int r = blockIdx.y, b = blockIdx.x;
    for (int i = threadIdx.x; i < ndst4; i += 256) cnt4[i] = 0;
    __syncthreads();
    const int e0 = b * EPB;
    const int ne = min(EPB, epr - e0);
    const int* dp = dst + (size_t)r * epr + e0;
    unsigned char* rp = rank8 + (size_t)r * epr + e0;
    for (int i = threadIdx.x; i < ne; i += 256) {
        int d = dp[i];
        unsigned int sh = (d & 3) * 8;
        unsigned int old = atomicAdd(&cnt4[d >> 2], 1u << sh);   // LDS atomic
        rp[i] = (unsigned char)((old >> sh) & 0xFFu);
    }
    __syncthreads();
    unsigned int* hp = hist + ((size_t)r * nb + b) * ndst4;
    for (int i = threadIdx.x; i < ndst4; i += 256) hp[i] = cnt4[i];
}

// ---------------------------------------------------------------------------
// Phase 2: per-(r,node) serial scan over the nb block-histograms.
// ---------------------------------------------------------------------------
__global__ __launch_bounds__(256) void scan_kernel(
    unsigned int* __restrict__ hist, int* __restrict__ cnt,
    int ndst, int ndst4, int nb)
{
    int id = blockIdx.x * 256 + threadIdx.x;
    if (id >= RREL * ndst) return;
    int r = id / ndst;
    int node = id - r * ndst;
    unsigned char* hb = (unsigned char*)hist;
    const size_t stride = (size_t)ndst4 * 4;
    unsigned char* p0 = hb + (size_t)r * nb * stride + node;
    unsigned int run = 0;
    for (int b = 0; b < nb; ++b) {
        unsigned char* pp = p0 + (size_t)b * stride;
        unsigned int c = *pp;
        *pp = (unsigned char)run;          // degree per node ~25, fits u8
        run += c;
    }
    cnt[id] = (int)run;                     // true (uncapped) degree
}

// ---------------------------------------------------------------------------
// Phase 3: slot = rank8[e] + prefix[dst]; scattered 4B store, no atomics.
// ---------------------------------------------------------------------------
__global__ __launch_bounds__(256) void scatter_kernel(
    const int* __restrict__ src, const int* __restrict__ dst,
    const unsigned char* __restrict__ rank8, const unsigned int* __restrict__ hist,
    int* __restrict__ ell, int epr, int ndst4, int nb)
{
    __shared__ unsigned int pre4[10240];
    const int r = blockIdx.y, b = blockIdx.x;
    const unsigned int* hp = hist + ((size_t)r * nb + b) * ndst4;
    for (int i = threadIdx.x; i < ndst4; i += 256) pre4[i] = hp[i];
    __syncthreads();
    const int e0 = b * EPB;
    const int ne = min(EPB, epr - e0);
    const size_t eb = (size_t)r * epr + e0;
    const unsigned char* pre = (const unsigned char*)pre4;
    const int ndst = ndst4 * 4;
    for (int i = threadIdx.x; i < ne; i += 256) {
        int d = dst[eb + i];
        int s = src[eb + i];
        int slot = (int)rank8[eb + i] + (int)pre[d];
        if (slot < CAP) ell[((size_t)r * ndst + d) * CAP + slot] = s;
    }
}

// ---------------------------------------------------------------------------
// x (fp32 [N][256]) -> xb (bf16, per-row 16B-chunk XOR-swizzled: c ^= row&7)
// ---------------------------------------------------------------------------
__global__ __launch_bounds__(256) void convx_kernel(
    const float* __restrict__ x, unsigned short* __restrict__ xb)
{
    int id  = blockIdx.x * 256 + threadIdx.x;
    int row = id >> 5;
    int c   = id & 31;
    const float4* xp = (const float4*)(x + ((size_t)row << 8) + (c << 3));
    float4 a = xp[0], b = xp[1];
    u16x4 o0, o1;
    o0.x = f2bf(a.x); o0.y = f2bf(a.y); o0.z = f2bf(a.z); o0.w = f2bf(a.w);
    o1.x = f2bf(b.x); o1.y = f2bf(b.y); o1.z = f2bf(b.z); o1.w = f2bf(b.w);
    int cs = c ^ (row & 7);
    u16x4* op = (u16x4*)(xb + ((size_t)row << 8) + (cs << 3));
    op[0] = o0; op[1] = o1;
}

// ---------------------------------------------------------------------------
// W [R][K][128] fp32 -> WtF: fragment-ordered bf16 B operands.
// ---------------------------------------------------------------------------
template<int K>
__global__ __launch_bounds__(256) void convwf_kernel(
    const float* __restrict__ W, unsigned short* __restrict__ WtF)
{
    constexpr int KS = K / 32;
    int id = blockIdx.x * 256 + threadIdx.x;       // (frag, lane)
    if (id >= RREL * KS * 8 * 64) return;
    int lane = id & 63;
    int fi   = id >> 6;
    int nblk = fi & 7;
    int rk   = fi >> 3;                            // r*KS + kki
    int kki  = rk & (KS - 1);
    int rr   = rk / KS;
    int n  = nblk * 16 + (lane & 15);
    int k0 = kki * 32 + (lane >> 4) * 8;
    unsigned short* op = WtF + (size_t)id * 8;
    #pragma unroll
    for (int j = 0; j < 8; ++j)
        op[j] = f2bf(W[((size_t)(rr * K + k0 + j)) * 128 + n]);
}

// ---------------------------------------------------------------------------
// GEMM: one block = 128 rows x ALL 512 cols (4 relations). 1024 thr, 16 waves.
// Output in PAIR layout: Mout[(r>>1)*Mpad + row][ (r&1)*128 + col ] (256/row)
// so each relation-pair's gather slice is a contiguous, L3-resident region.
// ---------------------------------------------------------------------------
template<int K>
__global__ __launch_bounds__(1024, 4) void gemm_kernel(
    const unsigned short* __restrict__ Ab,   // [Mpad][K] bf16, 16B-chunk swizzled
    const unsigned short* __restrict__ WtF,  // fragment-ordered
    unsigned short* __restrict__ Mout, int M)
{
    constexpr int NPH = K / 128;               // 2 (K=256) or 1 (K=128)
    constexpr int KS  = K / 32;
    __shared__ unsigned short As[NPH * 128 * 128];

    const int m0   = blockIdx.x * 128;
    const int tid  = threadIdx.x;
    const int lane = tid & 63;
    const int wave = tid >> 6;                 // 0..15

    const char* gbase = (const char*)Ab;
    #pragma unroll
    for (int h = 0; h < NPH; ++h) {
        #pragma unroll
        for (int j = 0; j < 2; ++j) {
            int L = j * 16384 + tid * 16;
            int row  = L >> 8;
            int boff = L & 255;
            gload_lds16(gbase + ((size_t)(m0 + row) * (K * 2) + h * 256 + boff),
                        (char*)As + h * 32768 + L);
        }
    }

    const int r    = wave & 3;
    const int nh   = (wave >> 2) & 1;
    const int mh   = (wave >> 3) & 1;
    const int wm   = mh * 64;
    const int wn   = nh * 64;
    const int lr   = lane & 15;
    const int kg   = lane >> 4;
    const int xorv = (lr & 7) << 4;
    const unsigned short* Wr = WtF + (size_t)r * KS * 8 * 512;

    f32x4 acc[4][4] = {};
    #pragma unroll
    for (int h = 0; h < NPH; ++h) {
        if (h == 0) {
            if (NPH == 2) asm volatile("s_waitcnt vmcnt(2)" ::: "memory");
            else          asm volatile("s_waitcnt vmcnt(0)" ::: "memory");
        } else {
            asm volatile("s_waitcnt vmcnt(0)" ::: "memory");
        }
        __builtin_amdgcn_s_barrier();
        __builtin_amdgcn_sched_barrier(0);
        const char* Ap = (const char*)As + h * 32768;
        #pragma unroll
        for (int ks = 0; ks < 4; ++ks) {
            bf16x8 af[4], bv[4];
            const int kb = (ks * 64 + kg * 16) ^ xorv;
            #pragma unroll
            for (int mi = 0; mi < 4; ++mi)
                af[mi] = *(const bf16x8*)(Ap + (wm + mi * 16 + lr) * 256 + kb);
            const int kk32 = h * 4 + ks;
            #pragma unroll
            for (int ni = 0; ni < 4; ++ni)
                bv[ni] = *(const bf16x8*)&Wr[((size_t)kk32 * 8 + nh * 4 + ni) * 512 + lane * 8];
            #pragma unroll
            for (int mi = 0; mi < 4; ++mi)
                #pragma unroll
                for (int ni = 0; ni < 4; ++ni)
                    acc[mi][ni] = __builtin_amdgcn_mfma_f32_16x16x32_bf16(
                        af[mi], bv[ni], acc[mi][ni], 0, 0, 0);
        }
    }

    // epilogue: pair layout
    const int pr  = r >> 1;
    const int rc  = (r & 1) * 128;
    const int rowoff = (lane >> 4) * 4;
    #pragma unroll
    for (int mi = 0; mi < 4; ++mi) {
        #pragma unroll
        for (int j = 0; j < 4; ++j) {
            int grow = m0 + wm + mi * 16 + rowoff + j;
            if (grow < M) {
                #pragma unroll
                for (int ni = 0; ni < 4; ++ni)
                    Mout[((size_t)pr * M + grow) * 256 + rc + wn + ni * 16 + lr]
                        = f2bf(acc[mi][ni][j]);
            }
        }
    }
}

// ---------------------------------------------------------------------------
// Gather pass over one relation PAIR (rbase, rbase+1). Block = 2 nodes x
// 2 relations (wave per (node, rel)). Mp = [Npad][256] contiguous pair slice
// (102 MB -> L3-resident). FIRST writes f32 partial; LAST adds partial,
// sum-of-bias, and writes output.
// ---------------------------------------------------------------------------
template<bool FIRST, bool LAST, bool OUT_F32>
__global__ __launch_bounds__(256) void gpass_kernel(
    const unsigned short* __restrict__ Mp,
    const int* __restrict__ ell, const int* __restrict__ cnt,
    int rbase, const float* __restrict__ bias,
    float* __restrict__ part, void* __restrict__ outp, int ndst)
{
    __shared__ float red[4][2][128];
    const int tid  = threadIdx.x;
    const int lane = tid & 63;
    const int wave = tid >> 6;
    const int rel  = wave & 1;
    const int nio  = wave >> 1;
    const int node = blockIdx.x * 2 + nio;
    const int half = lane >> 5;
    const int sub  = lane & 31;
    const int idx  = (rbase + rel) * ndst + node;
    const int c    = cnt[idx];
    const int deg  = c < CAP ? c : CAP;
    const int base = idx * CAP;
    const int coff = rel * 128 + sub * 4;    // element offset within 256-wide row

    float a0 = 0.f, a1 = 0.f, a2 = 0.f, a3 = 0.f;
    int e = 0;
    for (; e + 8 <= deg; e += 8) {
        int4 sa = *(const int4*)&ell[base + e];
        int4 sb = *(const int4*)&ell[base + e + 4];
        int sA = half ? sa.y : sa.x;
        int sB = half ? sa.w : sa.z;
        int sC = half ? sb.y : sb.x;
        int sD = half ? sb.w : sb.z;
        uint2 v0 = *(const uint2*)&Mp[(size_t)sA * 256 + coff];
        uint2 v1 = *(const uint2*)&Mp[(size_t)sB * 256 + coff];
        uint2 v2 = *(const uint2*)&Mp[(size_t)sC * 256 + coff];
        uint2 v3 = *(const uint2*)&Mp[(size_t)sD * 256 + coff];
        a0 += bflo(v0.x) + bflo(v1.x) + bflo(v2.x) + bflo(v3.x);
        a1 += bfhi(v0.x) + bfhi(v1.x) + bfhi(v2.x) + bfhi(v3.x);
        a2 += bflo(v0.y) + bflo(v1.y) + bflo(v2.y) + bflo(v3.y);
        a3 += bfhi(v0.y) + bfhi(v1.y) + bfhi(v2.y) + bfhi(v3.y);
    }
    for (; e < deg; e += 2) {
        int s0 = ell[base + e];
        int s1 = (e + 1 < deg) ? ell[base + e + 1] : -1;
        int s = half ? s1 : s0;
        if (s >= 0) {
            uint2 v = *(const uint2*)&Mp[(size_t)s * 256 + coff];
            a0 += bflo(v.x); a1 += bfhi(v.x);
            a2 += bflo(v.y); a3 += bfhi(v.y);
        }
    }
    float norm = c > 0 ? 1.0f / (float)c : 0.0f;
    red[wave][half][sub * 4 + 0] = a0 * norm;
    red[wave][half][sub * 4 + 1] = a1 * norm;
    red[wave][half][sub * 4 + 2] = a2 * norm;
    red[wave][half][sub * 4 + 3] = a3 * norm;
    __syncthreads();

    const int nn = tid >> 7, tt = tid & 127;
    const int onode = blockIdx.x * 2 + nn;
    float s = red[nn * 2 + 0][0][tt] + red[nn * 2 + 0][1][tt]
            + red[nn * 2 + 1][0][tt] + red[nn * 2 + 1][1][tt];
    if constexpr (!FIRST) s += part[(size_t)onode * 128 + tt];
    if constexpr (!LAST) {
        part[(size_t)onode * 128 + tt] = s;
    } else {
        s += bias[tt] + bias[128 + tt] + bias[256 + tt] + bias[384 + tt];
        if constexpr (OUT_F32) {
            ((float*)outp)[onode * 128 + tt] = s;
        } else {
            int cs = ((tt >> 3) ^ (onode & 7)) << 3;         // swizzled h layout
            ((unsigned short*)outp)[onode * 128 + cs + (tt & 7)] = f2bf(s);
        }
    }
}

// ---------------------------------------------------------------------------
extern "C" void kernel_launch(void* const* d_in, const int* in_sizes, int n_in,
                              void* d_out, int out_size, void* d_ws, size_t ws_size,
                              hipStream_t stream)
{
    const float* x  = (const float*)d_in[0];
    const float* W1 = (const float*)d_in[1];
    const float* b1 = (const float*)d_in[2];
    const float* W2 = (const float*)d_in[3];
    const float* b2 = (const float*)d_in[4];
    const int* src1 = (const int*)d_in[5];
    const int* dst1 = (const int*)d_in[6];
    const int* src2 = (const int*)d_in[7];
    const int* dst2 = (const int*)d_in[8];

    char* p = (char*)d_ws;
    auto alloc = [&](size_t bytes) {
        char* q = p; p += (bytes + 255) & ~(size_t)255; return q;
    };
    unsigned short* xb   = (unsigned short*)alloc((size_t)(N_SRC + 64) * 256 * 2);  // 102.4 MB
    unsigned short* m1   = (unsigned short*)alloc((size_t)N_SRC * 512 * 2);         // 204.8 MB (2 pair slices)
    int*            ell1 = (int*)alloc((size_t)RREL * N_MIDN * CAP * 4);            //  61.4 MB
    int*            cnt1 = (int*)alloc((size_t)RREL * N_MIDN * 4);
    unsigned short* h    = (unsigned short*)alloc((size_t)(N_MIDN + 64) * 128 * 2); //  10.3 MB
    unsigned short* wt1  = (unsigned short*)alloc((size_t)RREL * 8 * 8 * 64 * 8 * 2);  // 256 KB frag-ordered
    unsigned short* wt2  = (unsigned short*)alloc((size_t)RREL * 4 * 8 * 64 * 8 * 2);  // 128 KB
    // Layer-2 scratch + gather partials alias xb (xb dead after gemm1):
    char* q2 = (char*)xb;
    unsigned short* m2   = (unsigned short*)q2; q2 += (size_t)N_MIDN * 512 * 2;     //  41.0 MB
    int*            ell2 = (int*)q2;            q2 += (size_t)RREL * N_DSTN * CAP * 4;
    int*            cnt2 = (int*)q2;            q2 += (size_t)RREL * N_DSTN * 4 + 256;
    float*          part1 = (float*)q2;         q2 += (size_t)N_MIDN * 128 * 4;     //  20.5 MB
    float*          part2 = (float*)q2;         q2 += (size_t)N_DSTN * 128 * 4;     //   4.1 MB
    // Fill scratch aliases m1 (dead until gemm1 / after gather1):
    const int NB1 = (E1N + EPB - 1) / EPB;   // 123
    const int NB2 = (E2N + EPB - 1) / EPB;   // 25
    unsigned int*  hist  = (unsigned int*)m1;                          // <= 19.7 MB
    unsigned char* rank8 = (unsigned char*)m1 + 24 * 1024 * 1024;      // 4 MB

    convwf_kernel<256><<<64, 256, 0, stream>>>(W1, wt1);
    convwf_kernel<128><<<32, 256, 0, stream>>>(W2, wt2);
    convx_kernel<<<(N_SRC * 32) / 256, 256, 0, stream>>>(x, xb);

    // layer-1 ELL build (atomic-free counting sort)
    count_kernel  <<<dim3(NB1, RREL), 256, 0, stream>>>(dst1, rank8, hist, E1N, N_MIDN / 4, NB1);
    scan_kernel   <<<(RREL * N_MIDN + 255) / 256, 256, 0, stream>>>(hist, cnt1, N_MIDN, N_MIDN / 4, NB1);
    scatter_kernel<<<dim3(NB1, RREL), 256, 0, stream>>>(src1, dst1, rank8, hist, ell1, E1N, N_MIDN / 4, NB1);

    gemm_kernel<256><<<(N_SRC + 127) / 128, 1024, 0, stream>>>(xb, wt1, m1, N_SRC);
    // gather layer 1: two L3-resident passes over relation pairs
    gpass_kernel<true, false, false><<<N_MIDN / 2, 256, 0, stream>>>(
        m1, ell1, cnt1, 0, b1, part1, (void*)h, N_MIDN);
    gpass_kernel<false, true, false><<<N_MIDN / 2, 256, 0, stream>>>(
        m1 + (size_t)N_SRC * 256, ell1, cnt1, 2, b1, part1, (void*)h, N_MIDN);

    // layer-2 ELL build (hist/rank8 reuse m1 space; ell2/cnt2 alias xb)
    count_kernel  <<<dim3(NB2, RREL), 256, 0, stream>>>(dst2, rank8, hist, E2N, N_DSTN / 4, NB2);
    scan_kernel   <<<(RREL * N_DSTN + 255) / 256, 256, 0, stream>>>(hist, cnt2, N_DSTN, N_DSTN / 4, NB2);
    scatter_kernel<<<dim3(NB2, RREL), 256, 0, stream>>>(src2, dst2, rank8, hist, ell2, E2N, N_DSTN / 4, NB2);

    gemm_kernel<128><<<(N_MIDN + 127) / 128, 1024, 0, stream>>>(h, wt2, m2, N_MIDN);
    gpass_kernel<true, false, true><<<N_DSTN / 2, 256, 0, stream>>>(
        m2, ell2, cnt2, 0, b2, part2, d_out, N_DSTN);
    gpass_kernel<false, true, true><<<N_DSTN / 2, 256, 0, stream>>>(
        m2 + (size_t)N_MIDN * 256, ell2, cnt2, 2, b2, part2, d_out, N_DSTN);
}

// Round 8
// 548.285 us; speedup vs baseline: 1.0782x; 1.0782x over previous
//
#include <hip/hip_runtime.h>
#include <hip/hip_bf16.h>

#define N_SRC  200000
#define N_MIDN 40000
#define N_DSTN 8000
#define RREL   4
#define E1N    1000000
#define E2N    200000
#define CAP    96    // ELL capacity; mean degree 25, overflow prob negligible
#define EPB    8192  // edges per count/scatter block

typedef __attribute__((ext_vector_type(8))) short bf16x8;
typedef __attribute__((ext_vector_type(4))) float f32x4;
typedef __attribute__((ext_vector_type(4))) unsigned short u16x4;

__device__ __forceinline__ unsigned short f2bf(float f) {
    unsigned int u = __float_as_uint(f);
    u = (u + 0x7FFFu + ((u >> 16) & 1u)) >> 16;   // RNE
    return (unsigned short)u;
}

__device__ __forceinline__ float bflo(unsigned int u) { return __uint_as_float(u << 16); }
__device__ __forceinline__ float bfhi(unsigned int u) { return __uint_as_float(u & 0xFFFF0000u); }

__device__ __forceinline__ void gload_lds16(const void* g, void* l) {
    __builtin_amdgcn_global_load_lds((const __attribute__((address_space(1))) void*)g,
                                     (__attribute__((address_space(3))) void*)l, 16, 0, 0);
}

// ---------------------------------------------------------------------------
// Phase 1: per-(relation, 8K-edge block) LDS byte histogram of dst.
// ---------------------------------------------------------------------------
__global__ __launch_bounds__(256) void count_kernel(
    const int* __restrict__ dst, unsigned char* __restrict__ rank8,
    unsigned int* __restrict__ hist, int epr, int ndst4, int nb)
{
    __shared__ unsigned int cnt4[10240];   // up to 40960 nodes as packed u8
    const int r = blockIdx.y, b = blockIdx.x;
    for (int i = threadIdx.x; i < ndst4; i += 256) cnt4[i] = 0;
    __syncthreads();
    const int e0 = b * EPB;
    const int ne = min(EPB, epr - e0);
    const int* dp = dst + (size_t)r * epr + e0;
    unsigned char* rp = rank8 + (size_t)r * epr + e0;
    for (int i = threadIdx.x; i < ne; i += 256) {
        int d = dp[i];
        unsigned int sh = (d & 3) * 8;
        unsigned int old = atomicAdd(&cnt4[d >> 2], 1u << sh);   // LDS atomic
        rp[i] = (unsigned char)((old >> sh) & 0xFFu);
    }
    __syncthreads();
    unsigned int* hp = hist + ((size_t)r * nb + b) * ndst4;
    for (int i = threadIdx.x; i < ndst4; i += 256) hp[i] = cnt4[i];
}

// ---------------------------------------------------------------------------
// Phase 2: per-(r,node) serial scan over the nb block-histograms.
// ---------------------------------------------------------------------------
__global__ __launch_bounds__(256) void scan_kernel(
    unsigned int* __restrict__ hist, int* __restrict__ cnt,
    int ndst, int ndst4, int nb)
{
    int id = blockIdx.x * 256 + threadIdx.x;
    if (id >= RREL * ndst) return;
    int r = id / ndst;
    int node = id - r * ndst;
    unsigned char* hb = (unsigned char*)hist;
    const size_t stride = (size_t)ndst4 * 4;
    unsigned char* p0 = hb + (size_t)r * nb * stride + node;
    unsigned int run = 0;
    for (int b = 0; b < nb; ++b) {
        unsigned char* pp = p0 + (size_t)b * stride;
        unsigned int c = *pp;
        *pp = (unsigned char)run;          // degree per node ~25, fits u8
        run += c;
    }
    cnt[id] = (int)run;                     // true (uncapped) degree
}

// ---------------------------------------------------------------------------
// Phase 3: slot = rank8[e] + prefix[dst]; scattered 4B store, no atomics.
// ---------------------------------------------------------------------------
__global__ __launch_bounds__(256) void scatter_kernel(
    const int* __restrict__ src, const int* __restrict__ dst,
    const unsigned char* __restrict__ rank8, const unsigned int* __restrict__ hist,
    int* __restrict__ ell, int epr, int ndst4, int nb)
{
    __shared__ unsigned int pre4[10240];
    const int r = blockIdx.y, b = blockIdx.x;
    const unsigned int* hp = hist + ((size_t)r * nb + b) * ndst4;
    for (int i = threadIdx.x; i < ndst4; i += 256) pre4[i] = hp[i];
    __syncthreads();
    const int e0 = b * EPB;
    const int ne = min(EPB, epr - e0);
    const size_t eb = (size_t)r * epr + e0;
    const unsigned char* pre = (const unsigned char*)pre4;
    const int ndst = ndst4 * 4;
    for (int i = threadIdx.x; i < ne; i += 256) {
        int d = dst[eb + i];
        int s = src[eb + i];
        int slot = (int)rank8[eb + i] + (int)pre[d];
        if (slot < CAP) ell[((size_t)r * ndst + d) * CAP + slot] = s;
    }
}

// ---------------------------------------------------------------------------
// W [R][K][128] fp32 -> WtF: fragment-ordered bf16 B operands.
// ---------------------------------------------------------------------------
template<int K>
__global__ __launch_bounds__(256) void convwf_kernel(
    const float* __restrict__ W, unsigned short* __restrict__ WtF)
{
    constexpr int KS = K / 32;
    int id = blockIdx.x * 256 + threadIdx.x;       // (frag, lane)
    if (id >= RREL * KS * 8 * 64) return;
    int lane = id & 63;
    int fi   = id >> 6;
    int nblk = fi & 7;
    int rk   = fi >> 3;                            // r*KS + kki
    int kki  = rk & (KS - 1);
    int rr   = rk / KS;
    int n  = nblk * 16 + (lane & 15);
    int k0 = kki * 32 + (lane >> 4) * 8;
    unsigned short* op = WtF + (size_t)id * 8;
    #pragma unroll
    for (int j = 0; j < 8; ++j)
        op[j] = f2bf(W[((size_t)(rr * K + k0 + j)) * 128 + n]);
}

// ---------------------------------------------------------------------------
// GEMM1 (fused convert): A = x fp32 [M][256], reg-staged -> bf16 -> swizzled
// LDS (XOR chunk^row&7, matching the compute-side kb XOR). 1024 thr, 16 waves,
// 128 rows x 512 cols (all 4 relations). B = contiguous frag-ordered WtF (L2).
// ---------------------------------------------------------------------------
__global__ __launch_bounds__(1024, 4) void gemm1_kernel(
    const float* __restrict__ X,
    const unsigned short* __restrict__ WtF,
    unsigned short* __restrict__ Mout, int M)
{
    __shared__ unsigned short As[2 * 128 * 128];   // 64 KB, two 128-col phases

    const int m0  = blockIdx.x * 128;
    const int tid = threadIdx.x;

    // stage: 128 rows x 256 f32 = 8192 float4; 8 per thread, cvt->bf16,
    // ds_write_b64 at swizzled offset. 2 rounds of 4 loads for reg pressure.
    #pragma unroll
    for (int jj = 0; jj < 2; ++jj) {
        float4 v[4];
        #pragma unroll
        for (int j = 0; j < 4; ++j) {
            int id = jj * 4096 + j * 1024 + tid;
            int row = id >> 6, col4 = id & 63;
            int grow = m0 + row; if (grow >= M) grow = M - 1;
            v[j] = *(const float4*)&X[(size_t)grow * 256 + col4 * 4];
        }
        #pragma unroll
        for (int j = 0; j < 4; ++j) {
            int id = jj * 4096 + j * 1024 + tid;
            int row = id >> 6, col4 = id & 63;
            int h   = col4 >> 5, c4l = col4 & 31;
            u16x4 o;
            o.x = f2bf(v[j].x); o.y = f2bf(v[j].y);
            o.z = f2bf(v[j].z); o.w = f2bf(v[j].w);
            int b   = c4l * 8;                                  // byte in 256B phase-row
            int off = (((b >> 4) ^ (row & 7)) << 4) | (b & 15); // 16B-chunk XOR swizzle
            *(u16x4*)((char*)As + h * 32768 + row * 256 + off) = o;
        }
    }
    __syncthreads();

    const int lane = tid & 63;
    const int wave = tid >> 6;                 // 0..15
    const int r    = wave & 3;
    const int nh   = (wave >> 2) & 1;
    const int mh   = (wave >> 3) & 1;
    const int wm   = mh * 64;
    const int wn   = nh * 64;
    const int lr   = lane & 15;
    const int kg   = lane >> 4;
    const int xorv = (lr & 7) << 4;
    const unsigned short* Wr = WtF + (size_t)r * 8 * 8 * 512;

    f32x4 acc[4][4] = {};
    #pragma unroll
    for (int h = 0; h < 2; ++h) {
        const char* Ap = (const char*)As + h * 32768;
        #pragma unroll
        for (int ks = 0; ks < 4; ++ks) {
            bf16x8 af[4], bv[4];
            const int kb = (ks * 64 + kg * 16) ^ xorv;
            #pragma unroll
            for (int mi = 0; mi < 4; ++mi)
                af[mi] = *(const bf16x8*)(Ap + (wm + mi * 16 + lr) * 256 + kb);
            const int kk32 = h * 4 + ks;
            #pragma unroll
            for (int ni = 0; ni < 4; ++ni)
                bv[ni] = *(const bf16x8*)&Wr[((size_t)kk32 * 8 + nh * 4 + ni) * 512 + lane * 8];
            #pragma unroll
            for (int mi = 0; mi < 4; ++mi)
                #pragma unroll
                for (int ni = 0; ni < 4; ++ni)
                    acc[mi][ni] = __builtin_amdgcn_mfma_f32_16x16x32_bf16(
                        af[mi], bv[ni], acc[mi][ni], 0, 0, 0);
        }
    }

    // epilogue: C/D layout col=lane&15, row=(lane>>4)*4+j
    const int rowoff = (lane >> 4) * 4;
    #pragma unroll
    for (int mi = 0; mi < 4; ++mi) {
        #pragma unroll
        for (int j = 0; j < 4; ++j) {
            int grow = m0 + wm + mi * 16 + rowoff + j;
            if (grow < M) {
                #pragma unroll
                for (int ni = 0; ni < 4; ++ni)
                    Mout[(size_t)grow * 512 + r * 128 + wn + ni * 16 + lr]
                        = f2bf(acc[mi][ni][j]);
            }
        }
    }
}

// ---------------------------------------------------------------------------
// GEMM2: Ab = h (bf16 swizzled, padded) staged via global_load_lds. K=128.
// ---------------------------------------------------------------------------
__global__ __launch_bounds__(1024, 4) void gemm2_kernel(
    const unsigned short* __restrict__ Ab,
    const unsigned short* __restrict__ WtF,
    unsigned short* __restrict__ Mout, int M)
{
    __shared__ unsigned short As[128 * 128];   // 32 KB

    const int m0   = blockIdx.x * 128;
    const int tid  = threadIdx.x;

    #pragma unroll
    for (int j = 0; j < 2; ++j) {
        int L = j * 16384 + tid * 16;
        int row  = L >> 8;
        int boff = L & 255;
        gload_lds16((const char*)Ab + ((size_t)(m0 + row) * 256 + boff),
                    (char*)As + L);
    }

    const int lane = tid & 63;
    const int wave = tid >> 6;
    const int r    = wave & 3;
    const int nh   = (wave >> 2) & 1;
    const int mh   = (wave >> 3) & 1;
    const int wm   = mh * 64;
    const int wn   = nh * 64;
    const int lr   = lane & 15;
    const int kg   = lane >> 4;
    const int xorv = (lr & 7) << 4;
    const unsigned short* Wr = WtF + (size_t)r * 4 * 8 * 512;

    asm volatile("s_waitcnt vmcnt(0)" ::: "memory");
    __builtin_amdgcn_s_barrier();
    __builtin_amdgcn_sched_barrier(0);

    f32x4 acc[4][4] = {};
    #pragma unroll
    for (int ks = 0; ks < 4; ++ks) {
        bf16x8 af[4], bv[4];
        const int kb = (ks * 64 + kg * 16) ^ xorv;
        #pragma unroll
        for (int mi = 0; mi < 4; ++mi)
            af[mi] = *(const bf16x8*)((const char*)As + (wm + mi * 16 + lr) * 256 + kb);
        #pragma unroll
        for (int ni = 0; ni < 4; ++ni)
            bv[ni] = *(const bf16x8*)&Wr[((size_t)ks * 8 + nh * 4 + ni) * 512 + lane * 8];
        #pragma unroll
        for (int mi = 0; mi < 4; ++mi)
            #pragma unroll
            for (int ni = 0; ni < 4; ++ni)
                acc[mi][ni] = __builtin_amdgcn_mfma_f32_16x16x32_bf16(
                    af[mi], bv[ni], acc[mi][ni], 0, 0, 0);
    }

    const int rowoff = (lane >> 4) * 4;
    #pragma unroll
    for (int mi = 0; mi < 4; ++mi) {
        #pragma unroll
        for (int j = 0; j < 4; ++j) {
            int grow = m0 + wm + mi * 16 + rowoff + j;
            if (grow < M) {
                #pragma unroll
                for (int ni = 0; ni < 4; ++ni)
                    Mout[(size_t)grow * 512 + r * 128 + wn + ni * 16 + lr]
                        = f2bf(acc[mi][ni][j]);
            }
        }
    }
}

// ---------------------------------------------------------------------------
// Gather (round-6 form): block per dst node, wave w handles relation w.
// 8 edges/iter, lane-halves split across edge pairs (4 x dwordx2 in flight).
// ---------------------------------------------------------------------------
template<bool OUT_F32>
__global__ __launch_bounds__(256) void gather_kernel(
    const unsigned short* __restrict__ Mt,   // [n_src_side][512] bf16
    const int* __restrict__ ell, const int* __restrict__ cnt,
    const float* __restrict__ bias,          // [R][128]
    void* __restrict__ outp, int ndst)
{
    __shared__ float red[RREL][2][128];
    const int node = blockIdx.x;
    const int lane = threadIdx.x & 63;
    const int r    = threadIdx.x >> 6;
    const int half = lane >> 5;
    const int sub  = lane & 31;
    const int idx  = r * ndst + node;
    const int c    = cnt[idx];
    const int deg  = c < CAP ? c : CAP;
    const int base = idx * CAP;
    const int coff = r * 128 + sub * 4;      // element offset; 8B per lane

    float a0 = 0.f, a1 = 0.f, a2 = 0.f, a3 = 0.f;
    int e = 0;
    for (; e + 8 <= deg; e += 8) {
        int4 sa = *(const int4*)&ell[base + e];
        int4 sb = *(const int4*)&ell[base + e + 4];
        int sA = half ? sa.y : sa.x;
        int sB = half ? sa.w : sa.z;
        int sC = half ? sb.y : sb.x;
        int sD = half ? sb.w : sb.z;
        uint2 v0 = *(const uint2*)&Mt[(size_t)sA * 512 + coff];
        uint2 v1 = *(const uint2*)&Mt[(size_t)sB * 512 + coff];
        uint2 v2 = *(const uint2*)&Mt[(size_t)sC * 512 + coff];
        uint2 v3 = *(const uint2*)&Mt[(size_t)sD * 512 + coff];
        a0 += bflo(v0.x) + bflo(v1.x) + bflo(v2.x) + bflo(v3.x);
        a1 += bfhi(v0.x) + bfhi(v1.x) + bfhi(v2.x) + bfhi(v3.x);
        a2 += bflo(v0.y) + bflo(v1.y) + bflo(v2.y) + bflo(v3.y);
        a3 += bfhi(v0.y) + bfhi(v1.y) + bfhi(v2.y) + bfhi(v3.y);
    }
    for (; e < deg; e += 2) {
        int s0 = ell[base + e];
        int s1 = (e + 1 < deg) ? ell[base + e + 1] : -1;
        int s = half ? s1 : s0;
        if (s >= 0) {
            uint2 v = *(const uint2*)&Mt[(size_t)s * 512 + coff];
            a0 += bflo(v.x); a1 += bfhi(v.x);
            a2 += bflo(v.y); a3 += bfhi(v.y);
        }
    }
    float norm = c > 0 ? 1.0f / (float)c : 0.0f;
    red[r][half][sub * 4 + 0] = a0 * norm;
    red[r][half][sub * 4 + 1] = a1 * norm;
    red[r][half][sub * 4 + 2] = a2 * norm;
    red[r][half][sub * 4 + 3] = a3 * norm;
    __syncthreads();

    const int t = threadIdx.x;
    if (t < 128) {
        float s = red[0][0][t] + red[0][1][t] + red[1][0][t] + red[1][1][t]
                + red[2][0][t] + red[2][1][t] + red[3][0][t] + red[3][1][t]
                + bias[t] + bias[128 + t] + bias[256 + t] + bias[384 + t];
        if constexpr (OUT_F32) {
            ((float*)outp)[node * 128 + t] = s;
        } else {
            int cs = ((t >> 3) ^ (node & 7)) << 3;           // swizzled h layout
            ((unsigned short*)outp)[node * 128 + cs + (t & 7)] = f2bf(s);
        }
    }
}

// ---------------------------------------------------------------------------
extern "C" void kernel_launch(void* const* d_in, const int* in_sizes, int n_in,
                              void* d_out, int out_size, void* d_ws, size_t ws_size,
                              hipStream_t stream)
{
    const float* x  = (const float*)d_in[0];
    const float* W1 = (const float*)d_in[1];
    const float* b1 = (const float*)d_in[2];
    const float* W2 = (const float*)d_in[3];
    const float* b2 = (const float*)d_in[4];
    const int* src1 = (const int*)d_in[5];
    const int* dst1 = (const int*)d_in[6];
    const int* src2 = (const int*)d_in[7];
    const int* dst2 = (const int*)d_in[8];

    char* p = (char*)d_ws;
    auto alloc = [&](size_t bytes) {
        char* q = p; p += (bytes + 255) & ~(size_t)255; return q;
    };
    unsigned short* m1   = (unsigned short*)alloc((size_t)N_SRC * 512 * 2);         // 204.8 MB
    int*            ell1 = (int*)alloc((size_t)RREL * N_MIDN * CAP * 4);            //  61.4 MB
    int*            cnt1 = (int*)alloc((size_t)RREL * N_MIDN * 4);
    unsigned short* h    = (unsigned short*)alloc((size_t)(N_MIDN + 64) * 128 * 2); //  10.3 MB
    unsigned short* wt1  = (unsigned short*)alloc((size_t)RREL * 8 * 8 * 64 * 8 * 2);  // 256 KB
    unsigned short* wt2  = (unsigned short*)alloc((size_t)RREL * 4 * 8 * 64 * 8 * 2);  // 128 KB

    // hist/rank8 alias m1 (m1 written by gemm1 AFTER scatter1; dead again
    // after gather1, before count2). Layer-2 ELL/m2 also pack inside m1.
    const int NB1 = (E1N + EPB - 1) / EPB;   // 123
    const int NB2 = (E2N + EPB - 1) / EPB;   // 25
    unsigned int*  hist  = (unsigned int*)m1;                          // <= 19.7 MB
    unsigned char* rank8 = (unsigned char*)m1 + 24 * 1024 * 1024;      //  4 MB
    char* L2b = (char*)m1 + 32 * 1024 * 1024;
    int*            ell2 = (int*)L2b;                                  // 12.3 MB
    int*            cnt2 = (int*)(L2b + 13 * 1024 * 1024);             // 128 KB
    unsigned short* m2   = (unsigned short*)(L2b + 14 * 1024 * 1024);  // 41.0 MB

    convwf_kernel<256><<<64, 256, 0, stream>>>(W1, wt1);
    convwf_kernel<128><<<32, 256, 0, stream>>>(W2, wt2);

    // layer-1 ELL build (atomic-free counting sort)
    count_kernel  <<<dim3(NB1, RREL), 256, 0, stream>>>(dst1, rank8, hist, E1N, N_MIDN / 4, NB1);
    scan_kernel   <<<(RREL * N_MIDN + 255) / 256, 256, 0, stream>>>(hist, cnt1, N_MIDN, N_MIDN / 4, NB1);
    scatter_kernel<<<dim3(NB1, RREL), 256, 0, stream>>>(src1, dst1, rank8, hist, ell1, E1N, N_MIDN / 4, NB1);

    gemm1_kernel<<<(N_SRC + 127) / 128, 1024, 0, stream>>>(x, wt1, m1, N_SRC);
    gather_kernel<false><<<N_MIDN, 256, 0, stream>>>(m1, ell1, cnt1, b1, (void*)h, N_MIDN);

    // layer-2 ELL build (all scratch inside dead m1)
    count_kernel  <<<dim3(NB2, RREL), 256, 0, stream>>>(dst2, rank8, hist, E2N, N_DSTN / 4, NB2);
    scan_kernel   <<<(RREL * N_DSTN + 255) / 256, 256, 0, stream>>>(hist, cnt2, N_DSTN, N_DSTN / 4, NB2);
    scatter_kernel<<<dim3(NB2, RREL), 256, 0, stream>>>(src2, dst2, rank8, hist, ell2, E2N, N_DSTN / 4, NB2);

    gemm2_kernel<<<(N_MIDN + 127) / 128, 1024, 0, stream>>>(h, wt2, m2, N_MIDN);
    gather_kernel<true><<<N_DSTN, 256, 0, stream>>>(m2, ell2, cnt2, b2, d_out, N_DSTN);
}